// Round 9
// baseline (326.413 us; speedup 1.0000x reference)
//
#include <hip/hip_runtime.h>
#include <hip/hip_bf16.h>
#include <stdint.h>

// VQ: x [N=131072, D=64] fp32, E [D=64, K=1024] fp32.
// R9 = R7/R8 resubmitted (two consecutive container-infra failures; source
// audited clean — third attempt discriminates infra vs kernel-triggered).
// Design:
//  - R5's proven screen skeleton (16 rows/wave, hi/lo bf16 6-MFMA chain,
//    TAU=1e-3, exact-f64 refine).
//  - B fragments staged per 4-tile group into LDS, shared by all 4 waves
//    (global B traffic 2.1 GB -> 512 MB; in-loop B reads = ds_read_b128 with
//    immediate offsets). The x-staging LDS region is reused as the B stage
//    buffer (A-frags are in registers after the preamble).
//  - refine fused into the screen block (R6-proven) -> 2 kernels total.
// R6 lesson: 2 row-tiles/wave spilled (FETCH/WRITE +170 MB, occupancy 13%).
// Keep R5's register footprint; occupancy via launch_bounds(256,4).

typedef unsigned long long u64;
typedef short short8 __attribute__((ext_vector_type(8)));
typedef float f32x4 __attribute__((ext_vector_type(4)));

constexpr int D = 64;
constexpr int K = 1024;
constexpr int XS = 72;           // x-stage row stride in bf16 elems (144 B)
constexpr float TAU = 1e-3f;     // screen err ~1.5e-4 << TAU (R5-proven margin)

__device__ __forceinline__ unsigned short bf16_rne(float v) {
    uint32_t u = __float_as_uint(v);
    uint32_t r = u + 0x7FFFu + ((u >> 16) & 1u);
    return (unsigned short)(r >> 16);
}
__device__ __forceinline__ float bf16_f(unsigned short h) {
    return __uint_as_float(((uint32_t)h) << 16);
}
__device__ __forceinline__ uint32_t fmap(float v) {
    uint32_t u = __float_as_uint(v);
    return (u & 0x80000000u) ? ~u : (u | 0x80000000u);
}
__device__ __forceinline__ float funmap(uint32_t m) {
    uint32_t u = (m & 0x80000000u) ? (m ^ 0x80000000u) : ~m;
    return __uint_as_float(u);
}
__device__ __forceinline__ void top2_merge(u64& b, u64& s, u64 ob, u64 os) {
    if (ob < b) { s = (b < os) ? b : os; b = ob; }
    else        { s = (ob < s) ? ob : s; }
}
__device__ __forceinline__ u64 shfl_xor_u64(u64 v, int m) {
    uint32_t lo = (uint32_t)v, hi = (uint32_t)(v >> 32);
    lo = (uint32_t)__shfl_xor((int)lo, m, 64);
    hi = (uint32_t)__shfl_xor((int)hi, m, 64);
    return ((u64)hi << 32) | lo;
}
__device__ __forceinline__ double shfl_xor_f64(double v, int m) {
    int lo = __double2loint(v), hi = __double2hiint(v);
    lo = __shfl_xor(lo, m, 64);
    hi = __shfl_xor(hi, m, 64);
    return __hiloint2double(hi, lo);
}

// ---- prep: e_sq (f64/f32), ET[k][d] gather table, Bhi/Blo fragment-linear
//      bf16 tables of -2E (hi + residual lo). grid 256 x 256. (R5-proven) ----
__global__ __launch_bounds__(256) void vq_prep(const float* __restrict__ E,
                                               double* __restrict__ e_sq64,
                                               float* __restrict__ e_sq32,
                                               float* __restrict__ ET,
                                               unsigned short* __restrict__ Bhi,
                                               unsigned short* __restrict__ Blo) {
    int tid = blockIdx.x * 256 + threadIdx.x;        // 0..65535
    if (tid < K) {
        int k = tid;
        double s = 0.0;
        for (int d = 0; d < D; ++d) {
            float v = E[d * K + k];
            s = fma((double)v, (double)v, s);
            ET[k * D + d] = v;
        }
        e_sq64[k] = s;
        e_sq32[k] = (float)s;
    }
    // frag f = t*2+c, lane l, slot j: value=-2E[d][code], d=32c+8(l>>4)+j, code=16t+(l&15)
    {
        int j = tid & 7;
        int l = (tid >> 3) & 63;
        int f = tid >> 9;
        int c = f & 1;
        int t = f >> 1;
        int d = 32 * c + 8 * (l >> 4) + j;
        int code = 16 * t + (l & 15);
        float v = -2.0f * E[d * K + code];
        unsigned short h = bf16_rne(v);
        Bhi[tid] = h;
        Blo[tid] = bf16_rne(v - bf16_f(h));
    }
}

// ---- screen + fused refine: block = 64 rows (4 waves x 16), all 1024 codes ----
__global__ __launch_bounds__(256, 4) void vq_screen(
    const float* __restrict__ x, const float* __restrict__ E,
    const uint4* __restrict__ Bh4, const uint4* __restrict__ Bl4,
    const float* __restrict__ e_sq32, const double* __restrict__ e_sq64,
    const float* __restrict__ ET, float* __restrict__ out) {
    // regX: first holds x-stage (xhi 9216 B + xlo 9216 B), then reused as the
    // per-group B stage buffer (16384 B: hi [0,8192), lo [8192,16384)).
    __shared__ __align__(16) unsigned short regX[64 * XS * 2];   // 18432 B
    __shared__ float esq[K];                                     // 4 KB
    __shared__ int bk[64];
    __shared__ int lcount;
    __shared__ int llist[64];
    __shared__ double xs[D];
    __shared__ double wbv[4];
    __shared__ int wbk[4];
    __shared__ int bks;

    const int t0 = threadIdx.x;
    const int base = blockIdx.x * 64;
    unsigned short* xhi = regX;
    unsigned short* xlo = regX + 64 * XS;

    if (t0 == 0) lcount = 0;
    #pragma unroll
    for (int i = 0; i < 4; ++i) esq[i * 256 + t0] = e_sq32[i * 256 + t0];

    // stage x, split bf16 hi+lo (R5-proven body; 64 rows, thread = row-quarter)
    {
        int row = t0 >> 2, seg = t0 & 3;
        const float4* xp = (const float4*)(x + (size_t)(base + row) * D + seg * 16);
        short8 H0, H1, L0, L1;
        #pragma unroll
        for (int q = 0; q < 4; ++q) {
            float4 v = xp[q];
            float vv[4] = {v.x, v.y, v.z, v.w};
            #pragma unroll
            for (int e = 0; e < 4; ++e) {
                unsigned short h = bf16_rne(vv[e]);
                unsigned short lo = bf16_rne(vv[e] - bf16_f(h));
                int p = q * 4 + e;
                if (p < 8) { H0[p] = (short)h; L0[p] = (short)lo; }
                else       { H1[p - 8] = (short)h; L1[p - 8] = (short)lo; }
            }
        }
        int off = row * XS + seg * 16;
        *(short8*)&xhi[off] = H0;  *(short8*)&xhi[off + 8] = H1;
        *(short8*)&xlo[off] = L0;  *(short8*)&xlo[off + 8] = L1;
    }
    __syncthreads();

    const int wid = t0 >> 6, l = t0 & 63;
    const int col = l & 15, quad = l >> 4;

    // A fragments (verified layout: m = lane&15, k = quad*8 + j, chunks k0=0/32)
    const int arow = wid * 16 + col;
    short8 Ah0 = *(const short8*)&xhi[arow * XS + quad * 8];
    short8 Ah1 = *(const short8*)&xhi[arow * XS + 32 + quad * 8];
    short8 Al0 = *(const short8*)&xlo[arow * XS + quad * 8];
    short8 Al1 = *(const short8*)&xlo[arow * XS + 32 + quad * 8];
    __syncthreads();     // all A-frags read -> regX is now free for B staging

    float best[4], sec[4];
    int bidx[4];
    #pragma unroll
    for (int r = 0; r < 4; ++r) { best[r] = 3.4e38f; sec[r] = 3.4e38f; bidx[r] = 0; }

    const short8* SB = (const short8*)regX;   // stage view: hi slots [0,512), lo [512,1024)
    uint4* SW = (uint4*)regX;

    for (int g = 0; g < 16; ++g) {
        // stage group g (tiles 4g..4g+3): 8192 B hi + 8192 B lo, 64 B/thread
        {
            int sg = g * 512 + 2 * t0;
            uint4 h0 = Bh4[sg], h1 = Bh4[sg + 1];
            uint4 q0 = Bl4[sg], q1 = Bl4[sg + 1];
            SW[2 * t0] = h0;        SW[2 * t0 + 1] = h1;
            SW[512 + 2 * t0] = q0;  SW[512 + 2 * t0 + 1] = q1;
        }
        __syncthreads();
        #pragma unroll
        for (int tt = 0; tt < 4; ++tt) {
            int t = g * 4 + tt;
            short8 bh0 = SB[(tt * 2 + 0) * 64 + l];
            short8 bh1 = SB[(tt * 2 + 1) * 64 + l];
            short8 bl0 = SB[512 + (tt * 2 + 0) * 64 + l];
            short8 bl1 = SB[512 + (tt * 2 + 1) * 64 + l];
            float esv = esq[t * 16 + col];
            f32x4 C = {esv, esv, esv, esv};
            C = __builtin_amdgcn_mfma_f32_16x16x32_bf16(Ah0, bh0, C, 0, 0, 0);
            C = __builtin_amdgcn_mfma_f32_16x16x32_bf16(Ah1, bh1, C, 0, 0, 0);
            C = __builtin_amdgcn_mfma_f32_16x16x32_bf16(Ah0, bl0, C, 0, 0, 0);
            C = __builtin_amdgcn_mfma_f32_16x16x32_bf16(Ah1, bl1, C, 0, 0, 0);
            C = __builtin_amdgcn_mfma_f32_16x16x32_bf16(Al0, bh0, C, 0, 0, 0);
            C = __builtin_amdgcn_mfma_f32_16x16x32_bf16(Al1, bh1, C, 0, 0, 0);
            int tc = t * 16;
            #pragma unroll
            for (int r = 0; r < 4; ++r) {
                float v = C[r];
                bool lt = v < best[r];
                sec[r]  = __builtin_amdgcn_fmed3f(v, best[r], sec[r]);
                best[r] = fminf(v, best[r]);
                bidx[r] = lt ? tc : bidx[r];
            }
        }
        __syncthreads();   // protect next group's staging writes
    }

    // cross-lane top2 merge (masks 8..1 keep quad), flag ambiguous rows locally
    #pragma unroll
    for (int r = 0; r < 4; ++r) {
        u64 b = ((u64)fmap(best[r]) << 32) | (uint32_t)(bidx[r] + col);
        u64 s = ((u64)fmap(sec[r]) << 32) | 0xFFFFFFFFu;
        #pragma unroll
        for (int m = 8; m >= 1; m >>= 1) {
            u64 ob = shfl_xor_u64(b, m);
            u64 os = shfl_xor_u64(s, m);
            top2_merge(b, s, ob, os);
        }
        if (col == 0) {
            int rowL = wid * 16 + quad * 4 + r;       // verified C row map
            bk[rowL] = (int)(uint32_t)(b & 0xFFFFFFFFu);
            float vb = funmap((uint32_t)(b >> 32));
            float vs = funmap((uint32_t)(s >> 32));
            if (vs - vb < TAU) {
                int idx = atomicAdd(&lcount, 1);
                llist[idx] = rowL;                     // cap 64 = all rows
            }
        }
    }
    __syncthreads();

    // gather: thread t0 copies 64 B of its row from ET
    {
        int row = t0 >> 2, seg = t0 & 3;
        const float4* ep = (const float4*)(ET + (size_t)bk[row] * D + seg * 16);
        float4* op = (float4*)(out + (size_t)(base + row) * D + seg * 16);
        op[0] = ep[0]; op[1] = ep[1]; op[2] = ep[2]; op[3] = ep[3];
    }
    __syncthreads();

    // fused refine: exact fp64 argmin for this block's flagged rows (R6-proven)
    int nf = lcount;
    for (int i = 0; i < nf; ++i) {
        int row = base + llist[i];
        if (t0 < D) xs[t0] = (double)x[(size_t)row * D + t0];
        __syncthreads();
        double bv = 1.0e300; int bkk = 0;
        #pragma unroll
        for (int j = 0; j < 4; ++j) {
            int k = t0 * 4 + j;
            double a = 0.0;
            for (int d = 0; d < D; ++d)
                a = fma(xs[d], (double)E[d * K + k], a);
            double v = fma(-2.0, a, e_sq64[k]);
            if (v < bv) { bv = v; bkk = k; }
        }
        #pragma unroll
        for (int m = 32; m >= 1; m >>= 1) {
            double ov = shfl_xor_f64(bv, m);
            int    ok = __shfl_xor(bkk, m, 64);
            if (ov < bv || (ov == bv && ok < bkk)) { bv = ov; bkk = ok; }
        }
        if ((t0 & 63) == 0) { wbv[t0 >> 6] = bv; wbk[t0 >> 6] = bkk; }
        __syncthreads();
        if (t0 == 0) {
            double b0 = wbv[0]; int k0 = wbk[0];
            for (int w = 1; w < 4; ++w)
                if (wbv[w] < b0 || (wbv[w] == b0 && wbk[w] < k0)) { b0 = wbv[w]; k0 = wbk[w]; }
            bks = k0;
        }
        __syncthreads();
        if (t0 < D) out[(size_t)row * D + t0] = ET[(size_t)bks * D + t0];
        __syncthreads();
    }
}

extern "C" void kernel_launch(void* const* d_in, const int* in_sizes, int n_in,
                              void* d_out, int out_size, void* d_ws, size_t ws_size,
                              hipStream_t stream) {
    const float* x = (const float*)d_in[0];
    const float* E = (const float*)d_in[1];
    float* out = (float*)d_out;
    int N = in_sizes[0] / D;   // 131072

    // ws: e_sq64 8K | e_sq32 4K | ET 256K | Bhi 128K | Blo 128K
    char* w = (char*)d_ws;
    double*         e_sq64 = (double*)w;          w += K * sizeof(double);
    float*          e_sq32 = (float*)w;           w += K * sizeof(float);
    float*          ET     = (float*)w;           w += (size_t)K * D * sizeof(float);
    unsigned short* Bhi    = (unsigned short*)w;  w += (size_t)K * D * sizeof(unsigned short);
    unsigned short* Blo    = (unsigned short*)w;

    vq_prep<<<256, 256, 0, stream>>>(E, e_sq64, e_sq32, ET, Bhi, Blo);
    vq_screen<<<N / 64, 256, 0, stream>>>(x, E, (const uint4*)Bhi, (const uint4*)Blo,
                                          e_sq32, e_sq64, ET, out);
}